// Round 2
// baseline (61488.440 us; speedup 1.0000x reference)
//
#include <hip/hip_runtime.h>
#include <hip/hip_bf16.h>

// Problem: N=64, T=1024, I=512, H=512, P=256, 3H=1536.
// Folded recurrence (prev = h_t @ W_p.T + b_p folds into recurrent weights):
//   W_q = W_ip @ W_p   (W_ip = W_ih[:, 512:768])
//   W_big rows: [0:512)=W_hh_r+W_q_r, [512:1024)=W_hh_z+W_q_z,
//               [1024:1536)=W_q_n, [1536:2048)=W_hh_n
//   v_bp = b_p @ W_ip.T  (applies only for t>=1; at t=0 prev==0 exactly)
//   r = sig(x.wxr + h.w0 + b_ih[j]      + b_hh[j]      + vbp[j])
//   z = sig(x.wxz + h.w1 + b_ih[512+j]  + b_hh[512+j]  + vbp[512+j])
//   g = tanh(x.wxn + h.w2 + b_ih[1024+j] + vbp[1024+j] + r*(h.w3 + b_hh[1024+j]))
//   h' = (1-z)g + z h ;   out_t = h_{t+1} @ W_p.T + b_p  (fused into step t+1)
// All fp32 — numerically near-exact vs reference. Workspace need: ~4.5 MB.

typedef float f4 __attribute__((ext_vector_type(4)));

__device__ __forceinline__ float dot4(float4 a, float4 b, float acc) {
  return fmaf(a.x, b.x, fmaf(a.y, b.y, fmaf(a.z, b.z, fmaf(a.w, b.w, acc))));
}

// ---------- zero h_0 ----------
__global__ void k_init(float* __restrict__ H0) {
  int i = (blockIdx.x * 256 + threadIdx.x) * 4;
  *(float4*)&H0[i] = make_float4(0.f, 0.f, 0.f, 0.f);
}

// ---------- weight fold: W_q = W_ip @ W_p; assemble W_big; v_bp = b_p @ W_ip.T ----------
__global__ void k_fold(const float* __restrict__ W_ih, const float* __restrict__ W_hh,
                       const float* __restrict__ W_p, const float* __restrict__ b_p,
                       float* __restrict__ W_big, float* __restrict__ v_bp) {
  int idx = blockIdx.x * 256 + threadIdx.x;   // 1536*512 total
  int i = idx >> 9;          // 0..1535 (3H gate row)
  int j = idx & 511;         // 0..511  (H col)
  const float* wip = W_ih + (long)i * 768 + 512;   // W_ip row i (256 wide)
  float q = 0.f;
  for (int k = 0; k < 256; ++k) q = fmaf(wip[k], W_p[k * 512 + j], q);
  if (i < 1024) {
    W_big[(long)i * 512 + j] = W_hh[(long)i * 512 + j] + q;   // r,z combined
  } else {
    W_big[(long)i * 512 + j] = q;                             // W_q_n rows 1024..1535
    W_big[(long)(i + 512) * 512 + j] = W_hh[(long)i * 512 + j]; // W_hh_n rows 1536..2047
  }
  if (j == 0) {
    float s = 0.f;
    for (int k = 0; k < 256; ++k) s = fmaf(b_p[k], wip[k], s);
    v_bp[i] = s;
  }
}

// ---------- one recurrent step, fully fused (gi + gh + gates + out[t-1]) ----------
// grid 512 = 16 n-groups (4 rows) x 32 j-slices (16 cols); 256 threads = 4 k-quarters x 64 (n,j)
__launch_bounds__(256)
__global__ void k_step(int t,
                       const float* __restrict__ x,      // [64][1024][512]
                       const float* __restrict__ Hcur,   // [64][512] fp32
                       float* __restrict__ Hnext,        // [64][512] fp32
                       const float* __restrict__ W_big,  // [2048][512]
                       const float* __restrict__ W_ih,   // [1536][768]
                       const float* __restrict__ b_ih, const float* __restrict__ b_hh,
                       const float* __restrict__ v_bp,
                       const float* __restrict__ W_p,    // [256][512]
                       const float* __restrict__ b_p,
                       float* __restrict__ out) {        // [64][1024][256]
  __shared__ float hsf[4 * 512];
  __shared__ float xsf[4 * 512];
  __shared__ float red[3][64][8];
  __shared__ float pred_red[2][32];

  const int tid = threadIdx.x;
  const int n0 = (blockIdx.x >> 5) * 4;
  const int s  = blockIdx.x & 31;

  // stage h rows n0..n0+3 and x rows (n0..n0+3, t) — 2048 floats each
  {
    int base = tid * 8;
    *(float4*)&hsf[base]     = *(const float4*)&Hcur[n0 * 512 + base];
    *(float4*)&hsf[base + 4] = *(const float4*)&Hcur[n0 * 512 + base + 4];
    long xoff = ((long)(n0 + (base >> 9)) * 1024 + t) * 512 + (base & 511);
    *(float4*)&xsf[base]     = *(const float4*)&x[xoff];
    *(float4*)&xsf[base + 4] = *(const float4*)&x[xoff + 4];
  }
  __syncthreads();

  const int kh = tid >> 6;       // 0..3 (== wave id), k-quarter
  const int r  = tid & 63;
  const int ln = r >> 4;         // 0..3
  const int lj = r & 15;         // 0..15
  const int j  = s * 16 + lj;    // hidden col 0..511

  const float* w0 = W_big + (long)j * 512;
  const float* w1 = W_big + (long)(512 + j) * 512;
  const float* w2 = W_big + (long)(1024 + j) * 512;
  const float* w3 = W_big + (long)(1536 + j) * 512;
  const float* u0 = W_ih + (long)j * 768;
  const float* u1 = W_ih + (long)(512 + j) * 768;
  const float* u2 = W_ih + (long)(1024 + j) * 768;
  const float* hrow = hsf + ln * 512;
  const float* xrow = xsf + ln * 512;

  float a0 = 0.f, a1 = 0.f, a2 = 0.f, a3 = 0.f, a4 = 0.f, a5 = 0.f, a6 = 0.f;
  const int kb = kh * 128;
  for (int k = kb; k < kb + 128; k += 4) {
    float4 hv = *(const float4*)&hrow[k];
    float4 xv = *(const float4*)&xrow[k];
    a0 = dot4(hv, *(const float4*)&w0[k], a0);
    a1 = dot4(hv, *(const float4*)&w1[k], a1);
    a2 = dot4(hv, *(const float4*)&w2[k], a2);
    a3 = dot4(hv, *(const float4*)&w3[k], a3);
    a4 = dot4(xv, *(const float4*)&u0[k], a4);
    a5 = dot4(xv, *(const float4*)&u1[k], a5);
    a6 = dot4(xv, *(const float4*)&u2[k], a6);
  }
  if (kh) {
    float* rd = &red[kh - 1][r][0];
    rd[0] = a0; rd[1] = a1; rd[2] = a2; rd[3] = a3; rd[4] = a4; rd[5] = a5; rd[6] = a6;
  }
  __syncthreads();

  if (kh == 0) {
    for (int q = 0; q < 3; ++q) {
      const float* rd = &red[q][r][0];
      a0 += rd[0]; a1 += rd[1]; a2 += rd[2]; a3 += rd[3];
      a4 += rd[4]; a5 += rd[5]; a6 += rd[6];
    }
    float vb0 = 0.f, vb1 = 0.f, vb2 = 0.f;
    if (t >= 1) { vb0 = v_bp[j]; vb1 = v_bp[512 + j]; vb2 = v_bp[1024 + j]; }
    float rr = 1.f / (1.f + __expf(-(a4 + a0 + b_ih[j] + b_hh[j] + vb0)));
    float zz = 1.f / (1.f + __expf(-(a5 + a1 + b_ih[512 + j] + b_hh[512 + j] + vb1)));
    float gg = tanhf(a6 + a2 + b_ih[1024 + j] + vb2 + rr * (a3 + b_hh[1024 + j]));
    float hprev = hrow[j];
    float hn = (1.f - zz) * gg + zz * hprev;
    Hnext[(n0 + ln) * 512 + j] = hn;
  }

  // fused projection: out[t-1][n][p] = h_t[n] . W_p[p] + b_p[p], p-slice of 8 per block
  if (t >= 1 && (kh == 1 || kh == 2) && r < 32) {
    int pn = r >> 3, pp = r & 7;
    int p = s * 8 + pp;
    const float* wp = W_p + (long)p * 512;
    const float* hr = hsf + pn * 512;
    float acc = 0.f;
    int kb2 = (kh - 1) * 256;
    for (int k = kb2; k < kb2 + 256; k += 4)
      acc = dot4(*(const float4*)&hr[k], *(const float4*)&wp[k], acc);
    pred_red[kh - 1][r] = acc;
  }
  __syncthreads();
  if (t >= 1 && kh == 0 && r < 32) {
    int pn = r >> 3, pp = r & 7;
    int p = s * 8 + pp;
    out[((long)(n0 + pn) * 1024 + (t - 1)) * 256 + p] =
        pred_red[0][r] + pred_red[1][r] + b_p[p];
  }
}

// ---------- out[1023] from final h_1024 ----------
__global__ void k_lastout(const float* __restrict__ Hfin, const float* __restrict__ W_p,
                          const float* __restrict__ b_p, float* __restrict__ out) {
  __shared__ float hrow[512];
  const int n = blockIdx.x;
  const int tid = threadIdx.x;
  hrow[tid * 2]     = Hfin[n * 512 + tid * 2];
  hrow[tid * 2 + 1] = Hfin[n * 512 + tid * 2 + 1];
  __syncthreads();
  const float* wp = W_p + (long)tid * 512;
  float acc = 0.f;
  for (int k = 0; k < 512; k += 4)
    acc = dot4(*(const float4*)&hrow[k], *(const float4*)&wp[k], acc);
  out[((long)n * 1024 + 1023) * 256 + tid] = acc + b_p[tid];
}

extern "C" void kernel_launch(void* const* d_in, const int* in_sizes, int n_in,
                              void* d_out, int out_size, void* d_ws, size_t ws_size,
                              hipStream_t stream) {
  const float* x    = (const float*)d_in[0];
  // d_in[1] = text_lengths (all == T; unused by reference math)
  const float* W_ih = (const float*)d_in[2];
  const float* W_hh = (const float*)d_in[3];
  const float* b_ih = (const float*)d_in[4];
  const float* b_hh = (const float*)d_in[5];
  const float* W_p  = (const float*)d_in[6];
  const float* b_p  = (const float*)d_in[7];
  float* out = (float*)d_out;

  // workspace layout (bytes) — total need ~4.5 MB
  constexpr size_t OFF_WBIG  = 0;          // 2048*512*4 = 4,194,304
  constexpr size_t OFF_VBP   = 4194304;    // 1536*4 -> pad 8192
  constexpr size_t OFF_HPING = 4202496;    // 2*64*512*4 = 262,144
  constexpr size_t WS_NEED   = 4464640;
  if (ws_size < WS_NEED) return;  // zero output flags this case (absmax == max|ref| == 3.09)

  char* ws = (char*)d_ws;
  float* W_big = (float*)(ws + OFF_WBIG);
  float* v_bp  = (float*)(ws + OFF_VBP);
  float* Hping = (float*)(ws + OFF_HPING);

  k_init<<<32, 256, 0, stream>>>(Hping);                       // h_0 = 0 (slot 0)
  k_fold<<<3072, 256, 0, stream>>>(W_ih, W_hh, W_p, b_p, W_big, v_bp);

  for (int t = 0; t < 1024; ++t) {
    const float* hc = Hping + (size_t)(t & 1) * 32768;
    float* hn       = Hping + (size_t)((t + 1) & 1) * 32768;
    k_step<<<512, 256, 0, stream>>>(t, x, hc, hn, W_big, W_ih,
                                    b_ih, b_hh, v_bp, W_p, b_p, out);
  }
  // h_1024 lands in slot (1024 & 1) == 0
  k_lastout<<<64, 256, 0, stream>>>(Hping, W_p, b_p, out);
}

// Round 3
// 24611.673 us; speedup vs baseline: 2.4983x; 2.4983x over previous
//
#include <hip/hip_runtime.h>
#include <hip/hip_bf16.h>

// N=64, T=1024, I=512, H=512, P=256. Folded recurrence (verified R2):
//   W_q = W_ip @ W_p (W_ip = W_ih[:,512:768]); v_bp = b_p @ W_ip.T (t>=1 only)
//   W_big rows: [0:512)=Whh_r+Wq_r, [512:1024)=Whh_z+Wq_z, [1024:1536)=Wq_n, [1536:2048)=Whh_n
//   r = sig(x.Ur + h.w0 + bihr + bhhr + vbp_r); z = sig(x.Uz + h.w1 + bihz + bhhz + vbp_z)
//   g = tanh(x.Un + h.w2 + bihn + vbp_n + r*(h.w3 + bhhn)); h' = (1-z)g + z h
//   out_t = h_{t+1} @ W_p.T + b_p   (computed at step t+1 from the bf16 h broadcast)
// Persistent kernel: 64 blocks, grid barrier per step, h fp32 state in registers.

typedef short short8 __attribute__((ext_vector_type(8)));
typedef float f32x4 __attribute__((ext_vector_type(4)));

__device__ __forceinline__ unsigned short f2bf(float f) {
  __hip_bfloat16 h = __float2bfloat16(f);
  return *reinterpret_cast<unsigned short*>(&h);
}

// ---------- zero Hbf slot0/slot1 + cnt + dead (32,832 uints) ----------
__global__ void k_zero(unsigned int* __restrict__ p, int n) {
  int i = blockIdx.x * 256 + threadIdx.x;
  if (i < n) p[i] = 0u;
}

// ---------- weight fold (verified in R2): W_big fp32 [2048][512], v_bp[1536] ----------
__global__ void k_fold(const float* __restrict__ W_ih, const float* __restrict__ W_hh,
                       const float* __restrict__ W_p, const float* __restrict__ b_p,
                       float* __restrict__ W_big, float* __restrict__ v_bp) {
  int idx = blockIdx.x * 256 + threadIdx.x;   // 1536*512 total
  int i = idx >> 9;          // 0..1535 gate row
  int j = idx & 511;         // 0..511  col
  const float* wip = W_ih + (long)i * 768 + 512;
  float q = 0.f;
  for (int k = 0; k < 256; ++k) q = fmaf(wip[k], W_p[k * 512 + j], q);
  if (i < 1024) {
    W_big[(long)i * 512 + j] = W_hh[(long)i * 512 + j] + q;
  } else {
    W_big[(long)i * 512 + j] = q;
    W_big[(long)(i + 512) * 512 + j] = W_hh[(long)i * 512 + j];
  }
  if (j == 0) {
    float s = 0.f;
    for (int k = 0; k < 256; ++k) s = fmaf(b_p[k], wip[k], s);
    v_bp[i] = s;
  }
}

// ---------- pack per-block B-operand tiles, bf16: Wcat[b][T][c][k], T=0..4 ----------
// T0=[r8|z8](W_big), T1=[ni8|nh8](W_big), T2=[proj4|pad](W_p), T3=[xr8|xz8](W_ih), T4=[xn8|pad](W_ih)
__global__ void k_pack(const float* __restrict__ W_big, const float* __restrict__ W_ih,
                       const float* __restrict__ W_p, unsigned short* __restrict__ Wcat) {
  int e = blockIdx.x * 256 + threadIdx.x;   // 64*5*16*512 = 2,621,440 total
  int k = e & 511;
  int ccc = (e >> 9) & 15;
  int rest = e >> 13;         // 0..319
  int T = rest % 5, b = rest / 5;
  int j = b * 8 + (ccc & 7);
  bool hi = ccc >= 8;
  float v;
  if (T == 0)      v = W_big[(long)(hi ? 512 + j : j) * 512 + k];
  else if (T == 1) v = W_big[(long)(hi ? 1536 + j : 1024 + j) * 512 + k];
  else if (T == 2) v = (ccc < 4) ? W_p[(long)(b * 4 + ccc) * 512 + k] : 0.f;
  else if (T == 3) v = W_ih[(long)(hi ? 512 + j : j) * 768 + k];
  else             v = hi ? 0.f : W_ih[(long)(1024 + j) * 768 + k];
  Wcat[e] = f2bf(v);
}

// ---------- persistent recurrent kernel: 64 blocks x 256 threads ----------
__global__ __launch_bounds__(256, 1) void k_persist(
    const float* __restrict__ x,            // [64][1024][512] fp32
    const unsigned short* __restrict__ Wcat,
    const float* __restrict__ b_ih, const float* __restrict__ b_hh,
    const float* __restrict__ v_bp, const float* __restrict__ b_p,
    unsigned short* __restrict__ Hbf,       // [2][64][512] bf16 broadcast (slot0 zeroed)
    float* __restrict__ out,                // [64][1024][256]
    unsigned int* __restrict__ cnt, unsigned int* __restrict__ dead) {
  const int tid = threadIdx.x;
  const int b = blockIdx.x;                 // 0..63
  const int w = tid >> 6, lane = tid & 63;
  const int c = lane & 15, q = lane >> 4;
  const int n0 = w * 16;
  const int j0 = b * 8;
  const int pcol = b * 4 + (c & 3);

  // per-lane B-frag bases (within Wcat): tile row = c, k-chunk = q*8
  const long fragoff = (long)c * 512 + q * 8;
  const unsigned short* wt0 = Wcat + (long)(b * 5 + 0) * 8192 + fragoff;
  const unsigned short* wt1 = Wcat + (long)(b * 5 + 1) * 8192 + fragoff;
  const unsigned short* wt2 = Wcat + (long)(b * 5 + 2) * 8192 + fragoff;
  const unsigned short* wt3 = Wcat + (long)(b * 5 + 3) * 8192 + fragoff;
  const unsigned short* wt4 = Wcat + (long)(b * 5 + 4) * 8192 + fragoff;
  const float* xlane = x + (long)(n0 + c) * 1024 * 512 + q * 8;   // + t*512 + k0

  // hoisted biases (lanes c>=8 compute harmless duplicates)
  const int jj = j0 + (c & 7);
  const float bihr = b_ih[jj],        bhhr = b_hh[jj],        vbr = v_bp[jj];
  const float bihz = b_ih[512 + jj],  bhhz = b_hh[512 + jj],  vbz = v_bp[512 + jj];
  const float bihn = b_ih[1024 + jj], bhhn = b_hh[1024 + jj], vbn = v_bp[1024 + jj];
  const float bp = b_p[pcol];

  float hprev[4] = {0.f, 0.f, 0.f, 0.f};    // fp32 h state for (n0+q*4+r, j0+c), c<8
  bool alive = true;

  for (int t = 0; t <= 1024; ++t) {
    const int cur = t & 1, nxt = cur ^ 1;
    const unsigned short* hb = Hbf + (long)cur * 32768 + (long)(n0 + c) * 512 + q * 8;
    f32x4 a0{0.f,0.f,0.f,0.f}, a1 = a0, a2 = a0, a3 = a0, a4 = a0;
    const bool hasx = (t < 1024);
    const float* xr = xlane + (long)t * 512;
#pragma unroll 4
    for (int ki = 0; ki < 16; ++ki) {
      const int k0 = ki * 32;
      short8 ah = *(const short8*)(hb + k0);
      short8 w0v = *(const short8*)(wt0 + k0);
      short8 w1v = *(const short8*)(wt1 + k0);
      short8 w2v = *(const short8*)(wt2 + k0);
      a0 = __builtin_amdgcn_mfma_f32_16x16x32_bf16(ah, w0v, a0, 0, 0, 0);
      a1 = __builtin_amdgcn_mfma_f32_16x16x32_bf16(ah, w1v, a1, 0, 0, 0);
      a2 = __builtin_amdgcn_mfma_f32_16x16x32_bf16(ah, w2v, a2, 0, 0, 0);
      if (hasx) {
        float4 xa = *(const float4*)(xr + k0);
        float4 xb = *(const float4*)(xr + k0 + 4);
        short8 ax;
        ax[0] = f2bf(xa.x); ax[1] = f2bf(xa.y); ax[2] = f2bf(xa.z); ax[3] = f2bf(xa.w);
        ax[4] = f2bf(xb.x); ax[5] = f2bf(xb.y); ax[6] = f2bf(xb.z); ax[7] = f2bf(xb.w);
        short8 w3v = *(const short8*)(wt3 + k0);
        short8 w4v = *(const short8*)(wt4 + k0);
        a3 = __builtin_amdgcn_mfma_f32_16x16x32_bf16(ax, w3v, a3, 0, 0, 0);
        a4 = __builtin_amdgcn_mfma_f32_16x16x32_bf16(ax, w4v, a4, 0, 0, 0);
      }
    }

    // projection write: out[t-1][n][pcol] from a2 (A was h_t)
    if (t >= 1 && c < 4) {
#pragma unroll
      for (int r = 0; r < 4; ++r) {
        int n = n0 + q * 4 + r;
        out[((long)n * 1024 + (t - 1)) * 256 + pcol] = a2[r] + bp;
      }
    }
    if (t == 1024) break;

    // gates (c<8 lanes own (n, j0+c); partner lane c+8 holds z / nh accumulators)
    {
      const float vb_r = t ? vbr : 0.f, vb_z = t ? vbz : 0.f, vb_n = t ? vbn : 0.f;
#pragma unroll
      for (int r = 0; r < 4; ++r) {
        float vrz = a0[r] + a3[r];          // c<8: r-partial ; c>=8: z-partial
        float pz  = __shfl_xor(vrz, 8);
        float vni = a1[r];                  // c<8: ni ; c>=8: nh
        float pnh = __shfl_xor(vni, 8);
        if (c < 8) {
          int n = n0 + q * 4 + r;
          float rr = 1.f / (1.f + __expf(-(vrz + bihr + bhhr + vb_r)));
          float zz = 1.f / (1.f + __expf(-(pz + bihz + bhhz + vb_z)));
          float gg = tanhf(vni + a4[r] + bihn + vb_n + rr * (pnh + bhhn));
          float hn = (1.f - zz) * gg + zz * hprev[r];
          hprev[r] = hn;
          Hbf[(long)nxt * 32768 + (long)n * 512 + (j0 + c)] = f2bf(hn);
        }
      }
    }

    // grid barrier: monotonic counter, relaxed poll, acquire fence on exit
    __syncthreads();
    if (tid == 0 && alive) {
      __hip_atomic_fetch_add(cnt, 1u, __ATOMIC_ACQ_REL, __HIP_MEMORY_SCOPE_AGENT);
      const unsigned goal = 64u * (unsigned)(t + 1);
      int spins = 0;
      while (__hip_atomic_load(cnt, __ATOMIC_RELAXED, __HIP_MEMORY_SCOPE_AGENT) < goal) {
        __builtin_amdgcn_s_sleep(2);
        if ((++spins & 4095) == 0) {
          if (__hip_atomic_load(dead, __ATOMIC_RELAXED, __HIP_MEMORY_SCOPE_AGENT) != 0u) {
            alive = false; break;
          }
          if (spins > 1000000) {   // ~bounded wrong-answer instead of hang
            __hip_atomic_store(dead, 1u, __ATOMIC_RELAXED, __HIP_MEMORY_SCOPE_AGENT);
            alive = false; break;
          }
        }
      }
      __threadfence();   // acquire: invalidate stale L1/L2 before next step's h reads
    }
    __syncthreads();
  }
}

extern "C" void kernel_launch(void* const* d_in, const int* in_sizes, int n_in,
                              void* d_out, int out_size, void* d_ws, size_t ws_size,
                              hipStream_t stream) {
  const float* x    = (const float*)d_in[0];
  // d_in[1] = text_lengths (all == T; unused)
  const float* W_ih = (const float*)d_in[2];
  const float* W_hh = (const float*)d_in[3];
  const float* b_ih = (const float*)d_in[4];
  const float* b_hh = (const float*)d_in[5];
  const float* W_p  = (const float*)d_in[6];
  const float* b_p  = (const float*)d_in[7];
  float* out = (float*)d_out;

  // workspace layout (bytes), total ~9.6 MB
  constexpr size_t OFF_WBIG = 0;          // 2048*512*4   = 4,194,304
  constexpr size_t OFF_VBP  = 4194304;    // 1536*4 -> pad 8192
  constexpr size_t OFF_WCAT = 4202496;    // 64*5*16*512*2 = 5,242,880
  constexpr size_t OFF_HBF  = 9445376;    // 2*64*512*2   = 131,072
  constexpr size_t OFF_CNT  = 9576448;    // 128 (cnt @ +0, dead @ +64)
  constexpr size_t WS_NEED  = 9576576;
  if (ws_size < WS_NEED) return;          // zero out -> absmax == max|ref| flags this

  char* ws = (char*)d_ws;
  float* W_big         = (float*)(ws + OFF_WBIG);
  float* v_bp          = (float*)(ws + OFF_VBP);
  unsigned short* Wcat = (unsigned short*)(ws + OFF_WCAT);
  unsigned short* Hbf  = (unsigned short*)(ws + OFF_HBF);
  unsigned int* cnt    = (unsigned int*)(ws + OFF_CNT);
  unsigned int* dead   = (unsigned int*)(ws + OFF_CNT + 64);

  // zero Hbf (both slots) + cnt + dead: 32768 + 32 uints
  k_zero<<<129, 256, 0, stream>>>((unsigned int*)(ws + OFF_HBF), 32800);
  k_fold<<<3072, 256, 0, stream>>>(W_ih, W_hh, W_p, b_p, W_big, v_bp);
  k_pack<<<10240, 256, 0, stream>>>(W_big, W_ih, W_p, Wcat);
  k_persist<<<64, 256, 0, stream>>>(x, Wcat, b_ih, b_hh, v_bp, b_p, Hbf, out, cnt, dead);
}

// Round 4
// 12830.957 us; speedup vs baseline: 4.7922x; 1.9181x over previous
//
#include <hip/hip_runtime.h>
#include <hip/hip_bf16.h>

// N=64, T=1024, I=512, H=512, P=256. Folded recurrence (verified R2/R3):
//   W_q = W_ip @ W_p (W_ip = W_ih[:,512:768]); v_bp = b_p @ W_ip.T (t>=1 only)
//   W_big rows: [0:512)=Whh_r+Wq_r, [512:1024)=Whh_z+Wq_z, [1024:1536)=Wq_n, [1536:2048)=Whh_n
//   gi_x[t] = x_t @ W_ix.T  (W_ix = W_ih[:,0:512])  -- produced 1 step ahead by x-blocks
//   r = sig(gix_r + h.w0 + bihr + bhhr + vbp_r); z = sig(gix_z + h.w1 + bihz + bhhz + vbp_z)
//   g = tanh(gix_n + h.w2 + bihn + vbp_n + r*(h.w3 + bhhn)); h' = (1-z)g + z h
//   out_t = h_{t+1} @ W_p.T + b_p  (computed at step t+1 from the bf16 h broadcast)
// 160 persistent blocks: 64 recurrent (weights in VGPRs) + 96 x-producers.
// Grid barrier: distributed flags (64B-spaced stores) + generation broadcast —
// no atomic RMW contention (R3's 64 serialized fetch_adds cost ~22us/step).

typedef short short8 __attribute__((ext_vector_type(8)));
typedef float f32x4 __attribute__((ext_vector_type(4)));

__device__ __forceinline__ unsigned short f2bf(float f) {
  __hip_bfloat16 h = __float2bfloat16(f);
  return *reinterpret_cast<unsigned short*>(&h);
}

// ---------- zero Hbf + gix + flags + gen/dead ----------
__global__ void k_zero(unsigned int* __restrict__ p, int n) {
  int i = blockIdx.x * 256 + threadIdx.x;
  if (i < n) p[i] = 0u;
}

// ---------- weight fold (verified R2/R3) ----------
__global__ void k_fold(const float* __restrict__ W_ih, const float* __restrict__ W_hh,
                       const float* __restrict__ W_p, const float* __restrict__ b_p,
                       float* __restrict__ W_big, float* __restrict__ v_bp) {
  int idx = blockIdx.x * 256 + threadIdx.x;   // 1536*512 total
  int i = idx >> 9;
  int j = idx & 511;
  const float* wip = W_ih + (long)i * 768 + 512;
  float q = 0.f;
  for (int k = 0; k < 256; ++k) q = fmaf(wip[k], W_p[k * 512 + j], q);
  if (i < 1024) {
    W_big[(long)i * 512 + j] = W_hh[(long)i * 512 + j] + q;
  } else {
    W_big[(long)i * 512 + j] = q;
    W_big[(long)(i + 512) * 512 + j] = W_hh[(long)i * 512 + j];
  }
  if (j == 0) {
    float s = 0.f;
    for (int k = 0; k < 256; ++k) s = fmaf(b_p[k], wip[k], s);
    v_bp[i] = s;
  }
}

// ---------- pack bf16 weights ----------
// Wr[64 blocks][3 tiles][16 c][512 k]: T0=[r8|z8], T1=[ni8|nh8], T2=[proj4|pad12]  (R3-proven map)
// Wx[1536][512] = bf16 of W_ih[:, 0:512]
__global__ void k_pack(const float* __restrict__ W_big, const float* __restrict__ W_ih,
                       const float* __restrict__ W_p,
                       unsigned short* __restrict__ Wr, unsigned short* __restrict__ Wx) {
  long e = (long)blockIdx.x * 256 + threadIdx.x;   // 1,572,864 + 786,432 total
  if (e < 1572864) {
    int k = (int)(e & 511);
    int cc = (int)((e >> 9) & 15);
    int rest = (int)(e >> 13);        // 0..191
    int T = rest % 3, b = rest / 3;
    int j = b * 8 + (cc & 7);
    bool hi = cc >= 8;
    float v;
    if (T == 0)      v = W_big[(long)(hi ? 512 + j : j) * 512 + k];
    else if (T == 1) v = W_big[(long)(hi ? 1536 + j : 1024 + j) * 512 + k];
    else             v = (cc < 4) ? W_p[(long)(b * 4 + cc) * 512 + k] : 0.f;
    Wr[e] = f2bf(v);
  } else {
    long e2 = e - 1572864;            // over 1536*512
    int g = (int)(e2 >> 9), k = (int)(e2 & 511);
    Wx[e2] = f2bf(W_ih[(long)g * 768 + k]);
  }
}

// ---------- persistent kernel: blocks [0,64) recurrent, [64,160) x-producers ----------
__global__ __launch_bounds__(256, 1) void k_persist(
    const float* __restrict__ x,              // [64][1024][512] fp32
    const unsigned short* __restrict__ Wr, const unsigned short* __restrict__ Wx,
    const float* __restrict__ b_ih, const float* __restrict__ b_hh,
    const float* __restrict__ v_bp, const float* __restrict__ b_p,
    unsigned short* __restrict__ Hbf,         // [2][64][512] bf16 (slot0 zeroed)
    float* __restrict__ gix,                  // [2][64][1536] fp32 ping-pong
    float* __restrict__ out,                  // [64][1024][256]
    unsigned int* __restrict__ flags,         // 160 flags, 16-dword spacing
    unsigned int* __restrict__ gen, unsigned int* __restrict__ dead) {
  const int tid = threadIdx.x;
  const int blk = blockIdx.x;
  const int w = tid >> 6, lane = tid & 63, c = lane & 15, q = lane >> 4;
  __shared__ unsigned short xls[16][536];     // x-blocks only; pad 536 shorts (268 dwords)
  bool alive = true;
  unsigned int round = 0;

  // ---- barrier macro-equivalent (lambda) ----
  auto barrier = [&](unsigned int rnd) {
    __syncthreads();
    if (tid == 0 && alive)
      __hip_atomic_store(&flags[blk * 16], rnd, __ATOMIC_RELEASE, __HIP_MEMORY_SCOPE_AGENT);
    if (blk == 0) {
      if (tid < 160 && alive) {
        int spins = 0;
        while (__hip_atomic_load(&flags[tid * 16], __ATOMIC_RELAXED,
                                 __HIP_MEMORY_SCOPE_AGENT) < rnd) {
          __builtin_amdgcn_s_sleep(1);
          if ((++spins & 2047) == 0) {
            if (__hip_atomic_load(dead, __ATOMIC_RELAXED, __HIP_MEMORY_SCOPE_AGENT)) {
              alive = false; break;
            }
            if (spins > 1000000) {
              __hip_atomic_store(dead, 1u, __ATOMIC_RELAXED, __HIP_MEMORY_SCOPE_AGENT);
              alive = false; break;
            }
          }
        }
      }
      __syncthreads();
      if (tid == 0 && alive)
        __hip_atomic_store(gen, rnd, __ATOMIC_RELEASE, __HIP_MEMORY_SCOPE_AGENT);
    }
    if (tid == 0 && alive) {
      int spins = 0;
      while (__hip_atomic_load(gen, __ATOMIC_RELAXED, __HIP_MEMORY_SCOPE_AGENT) < rnd) {
        __builtin_amdgcn_s_sleep(1);
        if ((++spins & 2047) == 0) {
          if (__hip_atomic_load(dead, __ATOMIC_RELAXED, __HIP_MEMORY_SCOPE_AGENT)) {
            alive = false; break;
          }
          if (spins > 1000000) {
            __hip_atomic_store(dead, 1u, __ATOMIC_RELAXED, __HIP_MEMORY_SCOPE_AGENT);
            alive = false; break;
          }
        }
      }
      __threadfence();   // acquire: drop stale cached lines before reading peers' data
    }
    __syncthreads();
  };

  if (blk < 64) {
    // ================= recurrent block =================
    const int b = blk, j0 = b * 8, n0 = w * 16;
    const int pcol = b * 4 + (c & 3);
    // B-frags resident in VGPRs (192 regs)
    short8 wr0[16], wr1[16], wr2[16];
#pragma unroll
    for (int ki = 0; ki < 16; ++ki) {
      wr0[ki] = *(const short8*)(Wr + (((long)(b * 3 + 0) * 16 + c) * 512 + ki * 32 + q * 8));
      wr1[ki] = *(const short8*)(Wr + (((long)(b * 3 + 1) * 16 + c) * 512 + ki * 32 + q * 8));
      wr2[ki] = *(const short8*)(Wr + (((long)(b * 3 + 2) * 16 + c) * 512 + ki * 32 + q * 8));
    }
    const int jj = j0 + (c & 7);
    const float bihr = b_ih[jj],        bhhr = b_hh[jj],        vbr = v_bp[jj];
    const float bihz = b_ih[512 + jj],  bhhz = b_hh[512 + jj],  vbz = v_bp[512 + jj];
    const float bihn = b_ih[1024 + jj], bhhn = b_hh[1024 + jj], vbn = v_bp[1024 + jj];
    const float bp = b_p[pcol];
    float hprev[4] = {0.f, 0.f, 0.f, 0.f};

    barrier(++round);   // wait for gi_x[0]

    for (int t = 0; t <= 1024; ++t) {
      const int cur = t & 1;
      // early gi_x loads (post-fence, pre-MFMA so latency hides under MFMA)
      float gr[4], gz[4], gn[4];
      if (t < 1024) {
        const float* gp = gix + (long)cur * 98304;
#pragma unroll
        for (int r = 0; r < 4; ++r) {
          long nb = (long)(n0 + q * 4 + r) * 1536 + jj;
          gr[r] = gp[nb]; gz[r] = gp[nb + 512]; gn[r] = gp[nb + 1024];
        }
      }
      const unsigned short* hb = Hbf + (long)cur * 32768 + (long)(n0 + c) * 512 + q * 8;
      f32x4 a0{0.f, 0.f, 0.f, 0.f}, a1 = a0, a2 = a0;
#pragma unroll
      for (int ki = 0; ki < 16; ++ki) {
        short8 ah = *(const short8*)(hb + ki * 32);
        a0 = __builtin_amdgcn_mfma_f32_16x16x32_bf16(ah, wr0[ki], a0, 0, 0, 0);
        a1 = __builtin_amdgcn_mfma_f32_16x16x32_bf16(ah, wr1[ki], a1, 0, 0, 0);
        a2 = __builtin_amdgcn_mfma_f32_16x16x32_bf16(ah, wr2[ki], a2, 0, 0, 0);
      }
      if (t >= 1 && c < 4) {
#pragma unroll
        for (int r = 0; r < 4; ++r)
          out[((long)(n0 + q * 4 + r) * 1024 + (t - 1)) * 256 + pcol] = a2[r] + bp;
      }
      if (t == 1024) break;

      const float vb_r = t ? vbr : 0.f, vb_z = t ? vbz : 0.f, vb_n = t ? vbn : 0.f;
#pragma unroll
      for (int r = 0; r < 4; ++r) {
        float pz  = __shfl_xor(a0[r], 8);   // partner's z h-part
        float pnh = __shfl_xor(a1[r], 8);   // partner's nh h-part
        if (c < 8) {
          float rr = 1.f / (1.f + __expf(-(a0[r] + gr[r] + bihr + bhhr + vb_r)));
          float zz = 1.f / (1.f + __expf(-(pz + gz[r] + bihz + bhhz + vb_z)));
          float gg = tanhf(a1[r] + gn[r] + bihn + vb_n + rr * (pnh + bhhn));
          float hn = (1.f - zz) * gg + zz * hprev[r];
          hprev[r] = hn;
          Hbf[(long)(cur ^ 1) * 32768 + (long)(n0 + q * 4 + r) * 512 + (j0 + c)] = f2bf(hn);
        }
      }
      barrier(++round);
    }
  } else {
    // ================= x-producer block =================
    const int idx = blk - 64, mi = idx & 3, ji = idx >> 2;  // 4 m-groups x 24 j-groups
    short8 wx[16];
#pragma unroll
    for (int ki = 0; ki < 16; ++ki)
      wx[ki] = *(const short8*)(Wx + (((long)(ji * 4 + w) * 16 + c) * 512 + ki * 32 + q * 8));
    const int col = ji * 64 + w * 16 + c;
    const int srow = tid >> 4, scb = (tid & 15) * 32;   // staging: row, col-base

    auto produce = [&](int tt) {
      // stage x[16mi..+16][tt][:] to LDS bf16
      const float* xs = x + ((long)(16 * mi + srow) * 1024 + tt) * 512 + scb;
#pragma unroll
      for (int cc = 0; cc < 4; ++cc) {
        float4 fa = *(const float4*)(xs + cc * 8);
        float4 fb = *(const float4*)(xs + cc * 8 + 4);
        short8 sv;
        sv[0] = f2bf(fa.x); sv[1] = f2bf(fa.y); sv[2] = f2bf(fa.z); sv[3] = f2bf(fa.w);
        sv[4] = f2bf(fb.x); sv[5] = f2bf(fb.y); sv[6] = f2bf(fb.z); sv[7] = f2bf(fb.w);
        *(short8*)&xls[srow][scb + cc * 8] = sv;
      }
      __syncthreads();
      f32x4 acc{0.f, 0.f, 0.f, 0.f};
#pragma unroll
      for (int ki = 0; ki < 16; ++ki) {
        short8 ax = *(const short8*)&xls[c][ki * 32 + q * 8];
        acc = __builtin_amdgcn_mfma_f32_16x16x32_bf16(ax, wx[ki], acc, 0, 0, 0);
      }
      float* gp = gix + (long)(tt & 1) * 98304;
#pragma unroll
      for (int r = 0; r < 4; ++r)
        gp[(long)(16 * mi + q * 4 + r) * 1536 + col] = acc[r];
    };

    produce(0);
    barrier(++round);
    for (int t = 0; t < 1024; ++t) {
      if (t + 1 < 1024) produce(t + 1);
      barrier(++round);
    }
  }
}

extern "C" void kernel_launch(void* const* d_in, const int* in_sizes, int n_in,
                              void* d_out, int out_size, void* d_ws, size_t ws_size,
                              hipStream_t stream) {
  const float* x    = (const float*)d_in[0];
  // d_in[1] = text_lengths (all == T; unused)
  const float* W_ih = (const float*)d_in[2];
  const float* W_hh = (const float*)d_in[3];
  const float* b_ih = (const float*)d_in[4];
  const float* b_hh = (const float*)d_in[5];
  const float* W_p  = (const float*)d_in[6];
  const float* b_p  = (const float*)d_in[7];
  float* out = (float*)d_out;

  // workspace layout (bytes), total ~9.9 MB
  constexpr size_t OFF_WBIG = 0;           // 2048*512*4     = 4,194,304
  constexpr size_t OFF_VBP  = 4194304;     // 1536*4 -> pad 8,192
  constexpr size_t OFF_WR   = 4202496;     // 64*3*16*512*2  = 3,145,728
  constexpr size_t OFF_WX   = 7348224;     // 1536*512*2     = 1,572,864
  constexpr size_t OFF_HBF  = 8921088;     // 2*64*512*2     = 131,072
  constexpr size_t OFF_GIX  = 9052160;     // 2*64*1536*4    = 786,432
  constexpr size_t OFF_FLG  = 9838592;     // 256*64         = 16,384
  constexpr size_t OFF_GEN  = 9854976;     // gen @ +0, dead @ +64
  constexpr size_t WS_NEED  = 9855104;
  if (ws_size < WS_NEED) return;   // zero out -> absmax == max|ref| flags this

  char* ws = (char*)d_ws;
  float* W_big        = (float*)(ws + OFF_WBIG);
  float* v_bp         = (float*)(ws + OFF_VBP);
  unsigned short* Wr  = (unsigned short*)(ws + OFF_WR);
  unsigned short* Wx  = (unsigned short*)(ws + OFF_WX);
  unsigned short* Hbf = (unsigned short*)(ws + OFF_HBF);
  float* gix          = (float*)(ws + OFF_GIX);
  unsigned int* flags = (unsigned int*)(ws + OFF_FLG);
  unsigned int* gen   = (unsigned int*)(ws + OFF_GEN);
  unsigned int* dead  = (unsigned int*)(ws + OFF_GEN + 64);

  // zero Hbf + gix + flags + gen/dead (contiguous from OFF_HBF): 233,504 uints
  k_zero<<<913, 256, 0, stream>>>((unsigned int*)(ws + OFF_HBF), 233504);
  k_fold<<<3072, 256, 0, stream>>>(W_ih, W_hh, W_p, b_p, W_big, v_bp);
  k_pack<<<9216, 256, 0, stream>>>(W_big, W_ih, W_p, Wr, Wx);
  k_persist<<<160, 256, 0, stream>>>(x, Wr, Wx, b_ih, b_hh, v_bp, b_p,
                                     Hbf, gix, out, flags, gen, dead);
}